// Round 1
// baseline (195.282 us; speedup 1.0000x reference)
//
#include <hip/hip_runtime.h>

#define N_PTS 2048
#define BATCH 64

__global__ void zero_out_kernel(float* out) {
    if (threadIdx.x == 0) out[0] = 0.0f;
}

// grid: (CPB=2, BATCH, 2 directions), block: 256 threads.
// Each block: stage full "search side" (2048 x float4 = 32 KB) in LDS,
// each thread owns 4 query points, computes min-dist over all 2048 staged
// points, then block-reduces the sum of mins and atomicAdds to out[0].
__global__ __launch_bounds__(256) void chamfer_kernel(
        const float4* __restrict__ p,
        const float4* __restrict__ q,
        float* __restrict__ out) {
    __shared__ float4 sB[N_PTS];
    __shared__ float wsum[4];

    const int b   = blockIdx.y;
    const int dir = blockIdx.z;
    const float4* __restrict__ A  = dir ? q : p;   // query side
    const float4* __restrict__ Bm = dir ? p : q;   // search side
    const float4* __restrict__ Ab = A  + (size_t)b * N_PTS;
    const float4* __restrict__ Bb = Bm + (size_t)b * N_PTS;

    // cooperative staged load of the search side (coalesced float4)
    for (int j = threadIdx.x; j < N_PTS; j += 256) {
        sB[j] = Bb[j];
    }
    __syncthreads();

    // this block handles 1024 query points: base + t, +256, +512, +768
    const int base = blockIdx.x * (N_PTS / 2);

    float4 pt[4];
    float  mn[4];
#pragma unroll
    for (int k = 0; k < 4; ++k) {
        pt[k] = Ab[base + threadIdx.x + k * 256];
        mn[k] = 3.4e38f;
    }

#pragma unroll 4
    for (int j = 0; j < N_PTS; ++j) {
        const float4 qj = sB[j];   // wave-uniform broadcast read
#pragma unroll
        for (int k = 0; k < 4; ++k) {
            const float dx = pt[k].x - qj.x;
            const float dy = pt[k].y - qj.y;
            const float dz = pt[k].z - qj.z;
            const float dw = pt[k].w - qj.w;
            const float d  = dx * dx + dy * dy + dz * dz + dw * dw;
            mn[k] = fminf(mn[k], d);
        }
    }

    float s = mn[0] + mn[1] + mn[2] + mn[3];

    // wave (64-lane) shuffle reduction
#pragma unroll
    for (int off = 32; off > 0; off >>= 1) {
        s += __shfl_down(s, off, 64);
    }
    const int lane = threadIdx.x & 63;
    const int wid  = threadIdx.x >> 6;
    if (lane == 0) wsum[wid] = s;
    __syncthreads();
    if (threadIdx.x == 0) {
        const float blocksum = wsum[0] + wsum[1] + wsum[2] + wsum[3];
        atomicAdd(out, blocksum);
    }
}

// grid: (BATCH), block: 256. jet_diff = sum_n p - sum_n q per batch; add |diff|^2.
__global__ __launch_bounds__(256) void jet_kernel(
        const float4* __restrict__ p,
        const float4* __restrict__ q,
        float* __restrict__ out) {
    __shared__ float4 wacc[4];

    const int b = blockIdx.x;
    const float4* __restrict__ pb = p + (size_t)b * N_PTS;
    const float4* __restrict__ qb = q + (size_t)b * N_PTS;

    float ax = 0.f, ay = 0.f, az = 0.f, aw = 0.f;
    for (int j = threadIdx.x; j < N_PTS; j += 256) {
        const float4 pv = pb[j];
        const float4 qv = qb[j];
        ax += pv.x - qv.x;
        ay += pv.y - qv.y;
        az += pv.z - qv.z;
        aw += pv.w - qv.w;
    }
#pragma unroll
    for (int off = 32; off > 0; off >>= 1) {
        ax += __shfl_down(ax, off, 64);
        ay += __shfl_down(ay, off, 64);
        az += __shfl_down(az, off, 64);
        aw += __shfl_down(aw, off, 64);
    }
    const int lane = threadIdx.x & 63;
    const int wid  = threadIdx.x >> 6;
    if (lane == 0) wacc[wid] = make_float4(ax, ay, az, aw);
    __syncthreads();
    if (threadIdx.x == 0) {
        float dx = 0.f, dy = 0.f, dz = 0.f, dw = 0.f;
#pragma unroll
        for (int w = 0; w < 4; ++w) {
            dx += wacc[w].x;
            dy += wacc[w].y;
            dz += wacc[w].z;
            dw += wacc[w].w;
        }
        atomicAdd(out, dx * dx + dy * dy + dz * dz + dw * dw);
    }
}

extern "C" void kernel_launch(void* const* d_in, const int* in_sizes, int n_in,
                              void* d_out, int out_size, void* d_ws, size_t ws_size,
                              hipStream_t stream) {
    const float4* p = (const float4*)d_in[0];
    const float4* q = (const float4*)d_in[1];
    float* out = (float*)d_out;

    zero_out_kernel<<<1, 64, 0, stream>>>(out);
    chamfer_kernel<<<dim3(2, BATCH, 2), 256, 0, stream>>>(p, q, out);
    jet_kernel<<<dim3(BATCH), 256, 0, stream>>>(p, q, out);
}

// Round 2
// 126.320 us; speedup vs baseline: 1.5459x; 1.5459x over previous
//
#include <hip/hip_runtime.h>

#define N_PTS 2048
#define BATCH 64
#define P 2            // query points per thread
#define BLK 256        // threads per block
#define QPB (P * BLK)  // query points per block = 512

// grid: (N_PTS/QPB=4, BATCH, 2 directions), block: 256 threads.
// Inner pair op: t = qsq + (-2p)·q  (4 fma) + fmin  => 5 VALU ops/pair.
// |p|^2 of the query side is folded in once per query point.
// Blocks with (dir==0 && x==0) additionally compute the jet term for their
// batch (search side q_b is already staged in LDS).
__global__ __launch_bounds__(BLK) void chamfer_kernel(
        const float4* __restrict__ p,
        const float4* __restrict__ q,
        float* __restrict__ out) {
    __shared__ float4 sQ[N_PTS];     // search-side points (32 KB)
    __shared__ float4 sQs4[N_PTS/4]; // search-side |q|^2, float4-packed (8 KB)
    __shared__ float  wsum[4];
    __shared__ float4 wacc[4];

    const int tid = threadIdx.x;
    const int b   = blockIdx.y;
    const int dir = blockIdx.z;
    const float4* __restrict__ A  = dir ? q : p;   // query side
    const float4* __restrict__ Bm = dir ? p : q;   // search side
    const float4* __restrict__ Ab = A  + (size_t)b * N_PTS;
    const float4* __restrict__ Bb = Bm + (size_t)b * N_PTS;

    // stage search side + its squared norms (coalesced float4)
    float* sQsF = (float*)sQs4;
    for (int j = tid; j < N_PTS; j += BLK) {
        const float4 v = Bb[j];
        sQ[j] = v;
        sQsF[j] = v.x * v.x + v.y * v.y + v.z * v.z + v.w * v.w;
    }
    __syncthreads();

    const int base = blockIdx.x * QPB;

    float4 pm[P];    // -2 * query point
    float  mn[P];
    float  psq_sum = 0.0f;
#pragma unroll
    for (int k = 0; k < P; ++k) {
        const float4 pv = Ab[base + tid + k * BLK];
        psq_sum += pv.x * pv.x + pv.y * pv.y + pv.z * pv.z + pv.w * pv.w;
        pm[k] = make_float4(-2.0f * pv.x, -2.0f * pv.y, -2.0f * pv.z, -2.0f * pv.w);
        mn[k] = 3.4e38f;
    }

#define CHAMFER_STEP(JJ, QS)                                 \
    {                                                        \
        const float4 qv = sQ[(JJ)];                          \
        _Pragma("unroll")                                    \
        for (int k = 0; k < P; ++k) {                        \
            float t = fmaf(pm[k].x, qv.x, (QS));             \
            t = fmaf(pm[k].y, qv.y, t);                      \
            t = fmaf(pm[k].z, qv.z, t);                      \
            t = fmaf(pm[k].w, qv.w, t);                      \
            mn[k] = fminf(mn[k], t);                         \
        }                                                    \
    }

    for (int j = 0; j < N_PTS; j += 4) {
        const float4 qs4 = sQs4[j >> 2];
        CHAMFER_STEP(j + 0, qs4.x)
        CHAMFER_STEP(j + 1, qs4.y)
        CHAMFER_STEP(j + 2, qs4.z)
        CHAMFER_STEP(j + 3, qs4.w)
    }
#undef CHAMFER_STEP

    float s = psq_sum;
#pragma unroll
    for (int k = 0; k < P; ++k) s += mn[k];

    // wave (64-lane) shuffle reduction
#pragma unroll
    for (int off = 32; off > 0; off >>= 1) s += __shfl_down(s, off, 64);
    const int lane = tid & 63;
    const int wid  = tid >> 6;
    if (lane == 0) wsum[wid] = s;
    __syncthreads();
    if (tid == 0) {
        atomicAdd(out, wsum[0] + wsum[1] + wsum[2] + wsum[3]);
    }

    // ---- fused jet term: one block per batch does it ----
    if (dir == 0 && blockIdx.x == 0) {
        float ax = 0.f, ay = 0.f, az = 0.f, aw = 0.f;
        for (int j = tid; j < N_PTS; j += BLK) {
            const float4 pv = Ab[j];   // p side (L2-hot)
            const float4 qv = sQ[j];   // q side already staged
            ax += pv.x - qv.x;
            ay += pv.y - qv.y;
            az += pv.z - qv.z;
            aw += pv.w - qv.w;
        }
#pragma unroll
        for (int off = 32; off > 0; off >>= 1) {
            ax += __shfl_down(ax, off, 64);
            ay += __shfl_down(ay, off, 64);
            az += __shfl_down(az, off, 64);
            aw += __shfl_down(aw, off, 64);
        }
        if (lane == 0) wacc[wid] = make_float4(ax, ay, az, aw);
        __syncthreads();
        if (tid == 0) {
            float dx = 0.f, dy = 0.f, dz = 0.f, dw = 0.f;
#pragma unroll
            for (int w = 0; w < 4; ++w) {
                dx += wacc[w].x;
                dy += wacc[w].y;
                dz += wacc[w].z;
                dw += wacc[w].w;
            }
            atomicAdd(out, dx * dx + dy * dy + dz * dz + dw * dw);
        }
    }
}

extern "C" void kernel_launch(void* const* d_in, const int* in_sizes, int n_in,
                              void* d_out, int out_size, void* d_ws, size_t ws_size,
                              hipStream_t stream) {
    const float4* p = (const float4*)d_in[0];
    const float4* q = (const float4*)d_in[1];
    float* out = (float*)d_out;

    hipMemsetAsync(out, 0, sizeof(float), stream);
    chamfer_kernel<<<dim3(N_PTS / QPB, BATCH, 2), BLK, 0, stream>>>(p, q, out);
}